// Round 21
// baseline (158.582 us; speedup 1.0000x reference)
//
#include <hip/hip_runtime.h>
#include <math.h>

// MS-SSIM loss, 5 levels, 11-tap separable Gaussian (sigma=1.5), VALID padding.
// Round 21: r20 pipeline (L0 -> pool_pyramid -> fused rest -> finalize) with the
// L0 kernel widened to 4 input rows/iter: barriers & vmcnt drains per row halve,
// ring shift amortized, 4 independent h-conv chains. Safe now because L0's
// occupancy is GRID-capped (768 blocks = 3 blocks/CU = 12 waves/CU), so VGPR
// can grow to ~170 without losing waves (r10's cliff was grid-side, not here).
// 14-deep ring: slot j <-> output row 4k-10+j; row 4k+r -> slots r..r+10.
// 4-map transform (a=x+y, b=x-y -> P,Q,U,V), x2-rescaled emit algebra (exact).

struct GWin { float w[11]; };

// ---------------- L0: 4-row streaming SSIM + P1 ----------------
__global__ __launch_bounds__(256)
void ssim_l0_kernel(const float* __restrict__ X, const float* __restrict__ Y,
                    float* __restrict__ p1x, float* __restrict__ p1y,
                    float* __restrict__ accum, GWin gw)
{
    const int S = 512, outS = 502;
    __shared__ float4 ab[2][4][264];     // [slot][row 0..3][col-pair {a,b,a,b}]

    const int tid = threadIdx.x;
    const int ch  = blockIdx.z;
    const int oy0 = blockIdx.x * 64;
    const int gc  = 2 * tid;

    int rowsOut = outS - oy0; if (rowsOut > 64) rowsOut = 64;
    const int NIT = (rowsOut + 13) >> 2;     // 19 (full strips), 16 (last strip)

    const float* Xc = X + (size_t)ch * S * S;
    const float* Yc = Y + (size_t)ch * S * S;

    float2 sx[4], sy[4];                 // prefetched global rows

    auto issue = [&](int baseRow) {
        #pragma unroll
        for (int r = 0; r < 4; ++r) {
            int gr = baseRow + r; if (gr > S - 1) gr = S - 1;
            sx[r] = *reinterpret_cast<const float2*>(Xc + (size_t)gr * S + gc);
            sy[r] = *reinterpret_cast<const float2*>(Yc + (size_t)gr * S + gc);
        }
    };
    auto write_slot = [&](int sl) {      // one b128 per row
        #pragma unroll
        for (int r = 0; r < 4; ++r)
            ab[sl][r][tid] = make_float4(sx[r].x + sy[r].x, sx[r].x - sy[r].x,
                                         sx[r].y + sy[r].y, sx[r].y - sy[r].y);
    };

    // pending v-conv partials: [col][slot 0..13], all static-indexed
    float pendP[2][14], pendQ[2][14], pendU[2][14], pendV[2][14];
    #pragma unroll
    for (int c = 0; c < 2; ++c)
        #pragma unroll
        for (int j = 0; j < 14; ++j) { pendP[c][j] = 0.f; pendQ[c][j] = 0.f; pendU[c][j] = 0.f; pendV[c][j] = 0.f; }

    float ssum = 0.f, csum = 0.f;
    const float C1x2 = 2e-4f, C2x2 = 1.8e-3f;
    const bool ok0 = (gc    ) < outS;
    const bool ok1 = (gc + 1) < outS;

    // prologue (zero the 8 overrun units read by the last threads)
    if (tid < 8) {
        float4 z = make_float4(0.f, 0.f, 0.f, 0.f);
        #pragma unroll
        for (int r = 0; r < 4; ++r) { ab[0][r][256 + tid] = z; ab[1][r][256 + tid] = z; }
    }
    issue(oy0);
    write_slot(0);
    issue(oy0 + 4);
    __syncthreads();

    for (int k = 0; k < NIT; ++k) {
        const int sl = k & 1;

        // ---- h-conv for 4 staged rows: 6 ds_read_b128 per row ----
        float hP[4][2], hQ[4][2], hU[4][2], hV[4][2];
        float4 u0save[4];
        #pragma unroll
        for (int r = 0; r < 4; ++r) {
            const float4* bp = &ab[sl][r][tid];
            float4 u[6];
            #pragma unroll
            for (int i = 0; i < 6; ++i) u[i] = bp[i];
            u0save[r] = u[0];
            const float* v = reinterpret_cast<const float*>(u);  // v[2j]=a_j, v[2j+1]=b_j
            float sqa[12], sqb[12];
            #pragma unroll
            for (int j = 0; j < 12; ++j) {
                float a = v[2 * j], b = v[2 * j + 1];
                sqa[j] = a * a; sqb[j] = b * b;
            }
            float P0 = 0.f, Q0 = 0.f, U0 = 0.f, V0 = 0.f;
            float P1 = 0.f, Q1 = 0.f, U1 = 0.f, V1 = 0.f;
            #pragma unroll
            for (int t = 0; t < 11; ++t) {
                float wt = gw.w[t];
                P0 = fmaf(wt, v[2 * t],     P0);
                Q0 = fmaf(wt, v[2 * t + 1], Q0);
                U0 = fmaf(wt, sqa[t],       U0);
                V0 = fmaf(wt, sqb[t],       V0);
                P1 = fmaf(wt, v[2 * t + 2], P1);
                Q1 = fmaf(wt, v[2 * t + 3], Q1);
                U1 = fmaf(wt, sqa[t + 1],   U1);
                V1 = fmaf(wt, sqb[t + 1],   V1);
            }
            hP[r][0] = P0; hQ[r][0] = Q0; hU[r][0] = U0; hV[r][0] = V0;
            hP[r][1] = P1; hQ[r][1] = Q1; hU[r][1] = U1; hV[r][1] = V1;
        }

        // ---- v-accumulate: input row 4k+r -> slots j=r..r+10 with w[r+10-j] ----
        #pragma unroll
        for (int c = 0; c < 2; ++c)
            #pragma unroll
            for (int r = 0; r < 4; ++r)
                #pragma unroll
                for (int j = r; j <= r + 10; ++j) {
                    float wt = gw.w[r + 10 - j];
                    pendP[c][j] = fmaf(wt, hP[r][c], pendP[c][j]);
                    pendQ[c][j] = fmaf(wt, hQ[r][c], pendQ[c][j]);
                    pendU[c][j] = fmaf(wt, hU[r][c], pendU[c][j]);
                    pendV[c][j] = fmaf(wt, hV[r][c], pendV[c][j]);
                }

        // ---- emit 4 finished output rows: rel = 4k-10+e (x2-rescaled, exact) ----
        #pragma unroll
        for (int e = 0; e < 4; ++e) {
            int rel = 4 * k - 10 + e;
            bool rowok = (unsigned)rel < (unsigned)rowsOut;
            #pragma unroll
            for (int c = 0; c < 2; ++c) {
                float p = pendP[c][e], q = pendQ[c][e];
                float uu = pendU[c][e], vv = pendV[c][e];
                float p2 = p * p, q2 = q * q;
                float A = p2 - q2;                       // 2*(2 mu12)
                float csn = (uu - vv - A) + C2x2;        // 2*(2 sigma12) + 2C2
                float csd = (uu + vv - p2 - q2) + C2x2;
                float cs  = csn * __builtin_amdgcn_rcpf(csd);
                float ss  = (A + C1x2) * __builtin_amdgcn_rcpf(p2 + q2 + C1x2) * cs;
                if (rowok && (c ? ok1 : ok0)) { ssum += ss; csum += cs; }
            }
        }

        // ---- shift rings by 4 slots ----
        #pragma unroll
        for (int c = 0; c < 2; ++c) {
            #pragma unroll
            for (int j = 0; j < 10; ++j) {
                pendP[c][j] = pendP[c][j + 4]; pendQ[c][j] = pendQ[c][j + 4];
                pendU[c][j] = pendU[c][j + 4]; pendV[c][j] = pendV[c][j + 4];
            }
            #pragma unroll
            for (int j = 10; j < 14; ++j) {
                pendP[c][j] = 0.f; pendQ[c][j] = 0.f;
                pendU[c][j] = 0.f; pendV[c][j] = 0.f;
            }
        }

        // ---- 2x2 pool from registers: 2 pooled rows per iter ----
        if (k < 16) {
            float sa0 = u0save[0].x + u0save[0].z + u0save[1].x + u0save[1].z;
            float sb0 = u0save[0].y + u0save[0].w + u0save[1].y + u0save[1].w;
            float sa1 = u0save[2].x + u0save[2].z + u0save[3].x + u0save[3].z;
            float sb1 = u0save[2].y + u0save[2].w + u0save[3].y + u0save[3].w;
            int prow = (oy0 >> 1) + 2 * k;
            size_t o = (size_t)ch * 256 * 256 + (size_t)prow * 256 + tid;
            p1x[o]       = 0.125f * (sa0 + sb0);
            p1y[o]       = 0.125f * (sa0 - sb0);
            p1x[o + 256] = 0.125f * (sa1 + sb1);
            p1y[o + 256] = 0.125f * (sa1 - sb1);
        }

        // ---- stage next rows (vmcnt drain after all compute) ----
        if (k + 1 < NIT) {
            write_slot(sl ^ 1);
            if (k + 2 < NIT) issue(oy0 + 4 * (k + 2));
        }
        __syncthreads();
    }

    // ---- per-wave reduction + atomic accumulate ----
    for (int off = 32; off > 0; off >>= 1) {
        ssum += __shfl_down(ssum, off);
        csum += __shfl_down(csum, off);
    }
    if ((tid & 63) == 0) {
        atomicAdd(&accum[ch], ssum);
        atomicAdd(&accum[96 + ch], csum);
    }
}

// ------------- tiny hierarchical pool: P1 -> P2, P3, P4 -------------
__global__ __launch_bounds__(256)
void pool_pyramid_kernel(const float* __restrict__ p1x, const float* __restrict__ p1y,
                         float* __restrict__ p2x, float* __restrict__ p2y,
                         float* __restrict__ p3x, float* __restrict__ p3y,
                         float* __restrict__ p4x, float* __restrict__ p4y)
{
    const int tid  = threadIdx.x;
    const int ch   = blockIdx.y;                 // 96
    const int tile = blockIdx.x;                 // 16 tiles of 64x64 in 256x256
    const int ty0 = (tile >> 2) * 64, tx0 = (tile & 3) * 64;
    const int tr = tid >> 4, tc = tid & 15;      // 16x16 threads, each 4x4 input
    const int iy = ty0 + 4 * tr, ix = tx0 + 4 * tc;

    const float* X1 = p1x + (size_t)ch * 256 * 256;
    const float* Y1 = p1y + (size_t)ch * 256 * 256;

    float4 xr[4], yr[4];
    #pragma unroll
    for (int r = 0; r < 4; ++r) {
        xr[r] = *reinterpret_cast<const float4*>(X1 + (size_t)(iy + r) * 256 + ix);
        yr[r] = *reinterpret_cast<const float4*>(Y1 + (size_t)(iy + r) * 256 + ix);
    }

    // P2 (128x128): 2x2 outputs per thread
    float x200 = 0.25f * (xr[0].x + xr[0].y + xr[1].x + xr[1].y);
    float x201 = 0.25f * (xr[0].z + xr[0].w + xr[1].z + xr[1].w);
    float x210 = 0.25f * (xr[2].x + xr[2].y + xr[3].x + xr[3].y);
    float x211 = 0.25f * (xr[2].z + xr[2].w + xr[3].z + xr[3].w);
    float y200 = 0.25f * (yr[0].x + yr[0].y + yr[1].x + yr[1].y);
    float y201 = 0.25f * (yr[0].z + yr[0].w + yr[1].z + yr[1].w);
    float y210 = 0.25f * (yr[2].x + yr[2].y + yr[3].x + yr[3].y);
    float y211 = 0.25f * (yr[2].z + yr[2].w + yr[3].z + yr[3].w);
    {
        int oy = iy >> 1, ox = ix >> 1;
        float* bx = p2x + (size_t)ch * 128 * 128;
        float* by = p2y + (size_t)ch * 128 * 128;
        *reinterpret_cast<float2*>(bx + (size_t)oy * 128 + ox)       = make_float2(x200, x201);
        *reinterpret_cast<float2*>(bx + (size_t)(oy + 1) * 128 + ox) = make_float2(x210, x211);
        *reinterpret_cast<float2*>(by + (size_t)oy * 128 + ox)       = make_float2(y200, y201);
        *reinterpret_cast<float2*>(by + (size_t)(oy + 1) * 128 + ox) = make_float2(y210, y211);
    }

    // P3 (64x64): one output per thread
    float x3 = 0.25f * (x200 + x201 + x210 + x211);
    float y3 = 0.25f * (y200 + y201 + y210 + y211);
    p3x[(size_t)ch * 64 * 64 + (size_t)(iy >> 2) * 64 + (ix >> 2)] = x3;
    p3y[(size_t)ch * 64 * 64 + (size_t)(iy >> 2) * 64 + (ix >> 2)] = y3;

    // P4 (32x32): butterfly across tc (xor 1) and tr (xor 16)
    float x4 = x3 + __shfl_xor(x3, 1);
    float y4 = y3 + __shfl_xor(y3, 1);
    x4 += __shfl_xor(x4, 16);
    y4 += __shfl_xor(y4, 16);
    if (((tr | tc) & 1) == 0) {
        p4x[(size_t)ch * 32 * 32 + (size_t)(iy >> 3) * 32 + (ix >> 3)] = 0.25f * x4;
        p4y[(size_t)ch * 32 * 32 + (size_t)(iy >> 3) * 32 + (ix >> 3)] = 0.25f * y4;
    }
}

// ------------- Fused levels 1..4 kernel (no pooling, 630 blocks) -------------
__global__ __launch_bounds__(256)
void ssim_rest_kernel(const float* __restrict__ x1, const float* __restrict__ y1,
                      const float* __restrict__ x2, const float* __restrict__ y2,
                      const float* __restrict__ x3, const float* __restrict__ y3,
                      const float* __restrict__ x4, const float* __restrict__ y4,
                      float* __restrict__ accum, GWin gw)
{
    __shared__ float4 ab[2][2][264];

    const int bid = blockIdx.x;
    const int L = (bid >= 624) ? 3 : (bid >= 576) ? 2 : (bid >= 384) ? 1 : 0;
    const int off0 = (L == 0) ? 0 : (L == 1) ? 384 : (L == 2) ? 576 : 624;
    const int r = bid - off0;

    const int S      = (L == 0) ? 256 : (L == 1) ? 128 : (L == 2) ? 64 : 32;
    const int outS   = (L == 0) ? 246 : (L == 1) ? 118 : (L == 2) ? 54 : 22;
    const int rps    = (L == 0) ? 32  : (L == 1) ? 16  : (L == 2) ? 16 : 22;
    const int tpcLog = (L == 0) ? 7   : (L == 1) ? 6   : (L == 2) ? 5  : 4;
    const int stripsLog = (L == 0) ? 3 : (L == 1) ? 3 : (L == 2) ? 2 : 0;
    const float* Xl = (L == 0) ? x1 : (L == 1) ? x2 : (L == 2) ? x3 : x4;
    const float* Yl = (L == 0) ? y1 : (L == 1) ? y2 : (L == 2) ? y3 : y4;
    float* acc = accum + 192 * (L + 1);

    const int zidx  = r >> stripsLog;
    const int strip = r & ((1 << stripsLog) - 1);

    const int tid = threadIdx.x;
    const int tpc = 1 << tpcLog;
    const int lt  = tid & (tpc - 1);
    const int sub = tid >> tpcLog;
    const int ch  = zidx * (256 >> tpcLog) + sub;
    const int oy0 = strip * rps;
    const int gc  = 2 * lt;

    int rowsOut = outS - oy0; if (rowsOut > rps) rowsOut = rps;
    const int NIT = (rowsOut + 11) >> 1;

    const float* Xc = Xl + (size_t)ch * S * S;
    const float* Yc = Yl + (size_t)ch * S * S;

    float2 sx0, sy0, sx1, sy1;

    auto issue = [&](int baseRow) {
        int gr0 = baseRow;     if (gr0 > S - 1) gr0 = S - 1;
        int gr1 = baseRow + 1; if (gr1 > S - 1) gr1 = S - 1;
        sx0 = *reinterpret_cast<const float2*>(Xc + (size_t)gr0 * S + gc);
        sy0 = *reinterpret_cast<const float2*>(Yc + (size_t)gr0 * S + gc);
        sx1 = *reinterpret_cast<const float2*>(Xc + (size_t)gr1 * S + gc);
        sy1 = *reinterpret_cast<const float2*>(Yc + (size_t)gr1 * S + gc);
    };
    auto write_slot = [&](int sl) {
        ab[sl][0][tid] = make_float4(sx0.x + sy0.x, sx0.x - sy0.x,
                                     sx0.y + sy0.y, sx0.y - sy0.y);
        ab[sl][1][tid] = make_float4(sx1.x + sy1.x, sx1.x - sy1.x,
                                     sx1.y + sy1.y, sx1.y - sy1.y);
    };

    float pendP[2][12], pendQ[2][12], pendU[2][12], pendV[2][12];
    #pragma unroll
    for (int c = 0; c < 2; ++c)
        #pragma unroll
        for (int j = 0; j < 12; ++j) { pendP[c][j] = 0.f; pendQ[c][j] = 0.f; pendU[c][j] = 0.f; pendV[c][j] = 0.f; }

    float ssum = 0.f, csum = 0.f;
    const float C1x2 = 2e-4f, C2x2 = 1.8e-3f;
    const bool ok0 = gc < outS, ok1 = (gc + 1) < outS;

    if (tid < 8) {
        float4 z = make_float4(0.f, 0.f, 0.f, 0.f);
        ab[0][0][256 + tid] = z; ab[0][1][256 + tid] = z;
        ab[1][0][256 + tid] = z; ab[1][1][256 + tid] = z;
    }
    issue(oy0);
    write_slot(0);
    issue(oy0 + 2);
    __syncthreads();

    for (int k = 0; k < NIT; ++k) {
        const int sl = k & 1;

        float hP[2][2], hQ[2][2], hU[2][2], hV[2][2];
        #pragma unroll
        for (int r2 = 0; r2 < 2; ++r2) {
            const float4* bp = &ab[sl][r2][tid];
            float4 u[6];
            #pragma unroll
            for (int i = 0; i < 6; ++i) u[i] = bp[i];
            const float* v = reinterpret_cast<const float*>(u);
            float sqa[12], sqb[12];
            #pragma unroll
            for (int j = 0; j < 12; ++j) {
                float a = v[2 * j], b = v[2 * j + 1];
                sqa[j] = a * a; sqb[j] = b * b;
            }
            float P0 = 0.f, Q0 = 0.f, U0 = 0.f, V0 = 0.f;
            float P1 = 0.f, Q1 = 0.f, U1 = 0.f, V1 = 0.f;
            #pragma unroll
            for (int t = 0; t < 11; ++t) {
                float wt = gw.w[t];
                P0 = fmaf(wt, v[2 * t],     P0);
                Q0 = fmaf(wt, v[2 * t + 1], Q0);
                U0 = fmaf(wt, sqa[t],       U0);
                V0 = fmaf(wt, sqb[t],       V0);
                P1 = fmaf(wt, v[2 * t + 2], P1);
                Q1 = fmaf(wt, v[2 * t + 3], Q1);
                U1 = fmaf(wt, sqa[t + 1],   U1);
                V1 = fmaf(wt, sqb[t + 1],   V1);
            }
            hP[r2][0] = P0; hQ[r2][0] = Q0; hU[r2][0] = U0; hV[r2][0] = V0;
            hP[r2][1] = P1; hQ[r2][1] = Q1; hU[r2][1] = U1; hV[r2][1] = V1;
        }

        #pragma unroll
        for (int c = 0; c < 2; ++c) {
            #pragma unroll
            for (int j = 0; j <= 10; ++j) {
                float wt = gw.w[10 - j];
                pendP[c][j] = fmaf(wt, hP[0][c], pendP[c][j]);
                pendQ[c][j] = fmaf(wt, hQ[0][c], pendQ[c][j]);
                pendU[c][j] = fmaf(wt, hU[0][c], pendU[c][j]);
                pendV[c][j] = fmaf(wt, hV[0][c], pendV[c][j]);
            }
            #pragma unroll
            for (int j = 1; j <= 11; ++j) {
                float wt = gw.w[11 - j];
                pendP[c][j] = fmaf(wt, hP[1][c], pendP[c][j]);
                pendQ[c][j] = fmaf(wt, hQ[1][c], pendQ[c][j]);
                pendU[c][j] = fmaf(wt, hU[1][c], pendU[c][j]);
                pendV[c][j] = fmaf(wt, hV[1][c], pendV[c][j]);
            }
        }

        #pragma unroll
        for (int e = 0; e < 2; ++e) {
            int rel = 2 * k - 10 + e;
            bool rowok = (unsigned)rel < (unsigned)rowsOut;
            #pragma unroll
            for (int c = 0; c < 2; ++c) {
                float p = pendP[c][e], q = pendQ[c][e];
                float uu = pendU[c][e], vv = pendV[c][e];
                float p2 = p * p, q2 = q * q;
                float A = p2 - q2;
                float csn = (uu - vv - A) + C2x2;
                float csd = (uu + vv - p2 - q2) + C2x2;
                float cs  = csn * __builtin_amdgcn_rcpf(csd);
                float ss  = (A + C1x2) * __builtin_amdgcn_rcpf(p2 + q2 + C1x2) * cs;
                if (rowok && (c ? ok1 : ok0)) { ssum += ss; csum += cs; }
            }
        }

        #pragma unroll
        for (int c = 0; c < 2; ++c) {
            #pragma unroll
            for (int j = 0; j < 10; ++j) {
                pendP[c][j] = pendP[c][j + 2]; pendQ[c][j] = pendQ[c][j + 2];
                pendU[c][j] = pendU[c][j + 2]; pendV[c][j] = pendV[c][j + 2];
            }
            pendP[c][10] = 0.f; pendP[c][11] = 0.f;
            pendQ[c][10] = 0.f; pendQ[c][11] = 0.f;
            pendU[c][10] = 0.f; pendU[c][11] = 0.f;
            pendV[c][10] = 0.f; pendV[c][11] = 0.f;
        }

        if (k + 1 < NIT) {
            write_slot(sl ^ 1);
            if (k + 2 < NIT) issue(oy0 + 2 * (k + 2));
        }
        __syncthreads();
    }

    {
        int rw = (tpc < 64) ? tpc : 64;
        for (int off = rw >> 1; off > 0; off >>= 1) {
            ssum += __shfl_down(ssum, off);
            csum += __shfl_down(csum, off);
        }
        if ((lt & 63) == 0) {
            atomicAdd(&acc[ch], ssum);
            atomicAdd(&acc[96 + ch], csum);
        }
    }
}

__global__ void finalize_kernel(const float* __restrict__ accum, float* __restrict__ out)
{
    __shared__ float red[2];
    const int t = threadIdx.x;   // 128 threads
    const float w[5]   = {0.0448f, 0.2856f, 0.3001f, 0.2363f, 0.1333f};
    const float inv[5] = {1.f / (502.f * 502.f), 1.f / (246.f * 246.f),
                          1.f / (118.f * 118.f), 1.f / (54.f * 54.f),
                          1.f / (22.f * 22.f)};
    float ms = 0.f;
    if (t < 96) {
        ms = 1.f;
        #pragma unroll
        for (int l = 0; l < 5; ++l) {
            float v = (l < 4) ? accum[l * 192 + 96 + t] : accum[l * 192 + t];
            v *= inv[l];
            v = fmaxf(v, 0.f);
            ms *= powf(v, w[l]);
        }
    }
    for (int off = 32; off > 0; off >>= 1) ms += __shfl_down(ms, off);
    int wid = t >> 6, lane = t & 63;
    if (lane == 0) red[wid] = ms;
    __syncthreads();
    if (t == 0) out[0] = 1.f - (red[0] + red[1]) * (1.f / 96.f);
}

extern "C" void kernel_launch(void* const* d_in, const int* in_sizes, int n_in,
                              void* d_out, int out_size, void* d_ws, size_t ws_size,
                              hipStream_t stream)
{
    (void)in_sizes; (void)n_in; (void)out_size; (void)ws_size;
    const float* X = (const float*)d_in[0];
    const float* Y = (const float*)d_in[1];
    float* out = (float*)d_out;
    float* ws  = (float*)d_ws;

    // Gaussian window (size 11, sigma 1.5), normalized
    GWin gw;
    {
        double g[11], s = 0.0;
        for (int i = 0; i < 11; ++i) { double d = i - 5; g[i] = exp(-(d * d) / 4.5); s += g[i]; }
        for (int i = 0; i < 11; ++i) gw.w[i] = (float)(g[i] / s);
    }

    // workspace layout (floats): accum then pyramid buffers
    float* accum = ws;                 // L0 at +0, L1..L4 at +192*(L+1)
    size_t off = 1024;
    float* p1x = ws + off; off += (size_t)96 * 256 * 256;
    float* p1y = ws + off; off += (size_t)96 * 256 * 256;
    float* p2x = ws + off; off += (size_t)96 * 128 * 128;
    float* p2y = ws + off; off += (size_t)96 * 128 * 128;
    float* p3x = ws + off; off += (size_t)96 * 64 * 64;
    float* p3y = ws + off; off += (size_t)96 * 64 * 64;
    float* p4x = ws + off; off += (size_t)96 * 32 * 32;
    float* p4y = ws + off; off += (size_t)96 * 32 * 32;

    hipMemsetAsync(accum, 0, 5 * 192 * sizeof(float), stream);

    // L0: 4-row streaming kernel (writes P1), 8 strips x 96 channels
    ssim_l0_kernel<<<dim3(8, 1, 96), 256, 0, stream>>>(
        X, Y, p1x, p1y, accum, gw);

    // P1 -> P2, P3, P4 (hierarchical, shfl butterflies)
    pool_pyramid_kernel<<<dim3(16, 96), 256, 0, stream>>>(
        p1x, p1y, p2x, p2y, p3x, p3y, p4x, p4y);

    // L1..L4 fused: 384 + 192 + 48 + 6 = 630 blocks
    ssim_rest_kernel<<<dim3(630), 256, 0, stream>>>(
        p1x, p1y, p2x, p2y, p3x, p3y, p4x, p4y, accum, gw);

    finalize_kernel<<<1, 128, 0, stream>>>(accum, out);
}

// Round 22
// 156.850 us; speedup vs baseline: 1.0110x; 1.0110x over previous
//
#include <hip/hip_runtime.h>
#include <math.h>

// MS-SSIM loss, 5 levels, 11-tap separable Gaussian (sigma=1.5), VALID padding.
// Round 22: r20 pipeline with a BARRIER-FREE L0. Each wave owns a private
// 128-output-col band (+10 halo) with wave-private double-buffered LDS slots;
// r15's efficient body (2 cols/thread, 6 ds_read_b128/row, col-pair units).
// No __syncthreads in L0: one wave's DS ops complete in order, all LDS traffic
// is wave-private, so waves free-run and their DS bursts de-correlate (the
// per-iter barrier made all 4 waves flood the DS queue simultaneously).
// 4-map transform (a=x+y, b=x-y -> P,Q,U,V), x2-rescaled emit algebra (exact).

struct GWin { float w[11]; };

// ---------------- L0: barrier-free wave-band streaming SSIM + P1 ----------------
__global__ __launch_bounds__(256)
void ssim_l0_kernel(const float* __restrict__ X, const float* __restrict__ Y,
                    float* __restrict__ p1x, float* __restrict__ p1y,
                    float* __restrict__ accum, GWin gw)
{
    const int S = 512, outS = 502;
    __shared__ float4 ab[4][2][2][70];   // [wave][slot][row01][col-pair unit]

    const int tid = threadIdx.x;
    const int w   = tid >> 6;            // wave id 0..3
    const int ln  = tid & 63;            // lane
    const int ch  = blockIdx.z;
    const int oy0 = blockIdx.x * 64;
    const int gxb = 128 * w;             // wave's band base input col
    const int gc  = gxb + 2 * ln;        // thread's base output col

    int rowsOut = outS - oy0; if (rowsOut > 64) rowsOut = 64;
    const int NIT = (rowsOut + 11) >> 1; // 37 full strips, 32 last strip

    const float* Xc = X + (size_t)ch * S * S;
    const float* Yc = Y + (size_t)ch * S * S;

    // staging decode: 138 unit-tasks (2 rows x 69 units) over 64 lanes
    //   t0 = ln        -> row 0, unit ln
    //   t1 = ln + 64   -> row (ln>=5), unit (ln>=5 ? ln-5 : ln+64)
    //   t2 = ln + 128  -> row 1, unit 59+ln        (only ln < 10)
    const int  r1_ = (ln >= 5) ? 1 : 0;
    const int  u1_ = (ln >= 5) ? (ln - 5) : (ln + 64);
    const bool hasT2 = (ln < 10);
    const int  u2_ = 59 + ln;

    float2 sx0, sy0, sx1, sy1, sx2, sy2;

    auto ld1 = [&](int baseRow, int rr, int uu, float2& xo, float2& yo) {
        int gr = baseRow + rr; if (gr > S - 1) gr = S - 1;
        int gcol = gxb + 2 * uu; if (gcol > S - 2) gcol = S - 2;   // clamped cols feed only discarded outputs
        xo = *reinterpret_cast<const float2*>(Xc + (size_t)gr * S + gcol);
        yo = *reinterpret_cast<const float2*>(Yc + (size_t)gr * S + gcol);
    };
    auto issue = [&](int baseRow) {
        ld1(baseRow, 0,   ln,  sx0, sy0);
        ld1(baseRow, r1_, u1_, sx1, sy1);
        if (hasT2) ld1(baseRow, 1, u2_, sx2, sy2);
    };
    auto pack = [](float2 x, float2 y) {
        return make_float4(x.x + y.x, x.x - y.x, x.y + y.y, x.y - y.y);
    };
    auto write_slot = [&](int sl) {
        ab[w][sl][0][ln]    = pack(sx0, sy0);
        ab[w][sl][r1_][u1_] = pack(sx1, sy1);
        if (hasT2) ab[w][sl][1][u2_] = pack(sx2, sy2);
    };

    // pending v-conv partials: [col][slot], all static-indexed
    float pendP[2][12], pendQ[2][12], pendU[2][12], pendV[2][12];
    #pragma unroll
    for (int c = 0; c < 2; ++c)
        #pragma unroll
        for (int j = 0; j < 12; ++j) { pendP[c][j] = 0.f; pendQ[c][j] = 0.f; pendU[c][j] = 0.f; pendV[c][j] = 0.f; }

    float ssum = 0.f, csum = 0.f;
    const float C1x2 = 2e-4f, C2x2 = 1.8e-3f;
    const bool ok0 = (gc    ) < outS;
    const bool ok1 = (gc + 1) < outS;

    // prologue (wave-private; no barrier needed anywhere)
    issue(oy0);
    write_slot(0);
    issue(oy0 + 2);

    for (int k = 0; k < NIT; ++k) {
        const int sl = k & 1;

        // ---- h-conv for both staged rows: 6 ds_read_b128 per row ----
        float hP[2][2], hQ[2][2], hU[2][2], hV[2][2];   // [row][col]
        float4 u0save[2];
        #pragma unroll
        for (int r = 0; r < 2; ++r) {
            const float4* bp = &ab[w][sl][r][ln];
            float4 u[6];
            #pragma unroll
            for (int i = 0; i < 6; ++i) u[i] = bp[i];
            u0save[r] = u[0];
            const float* v = reinterpret_cast<const float*>(u);  // v[2j]=a_j, v[2j+1]=b_j
            float sqa[12], sqb[12];
            #pragma unroll
            for (int j = 0; j < 12; ++j) {
                float a = v[2 * j], b = v[2 * j + 1];
                sqa[j] = a * a; sqb[j] = b * b;
            }
            float P0 = 0.f, Q0 = 0.f, U0 = 0.f, V0 = 0.f;
            float P1 = 0.f, Q1 = 0.f, U1 = 0.f, V1 = 0.f;
            #pragma unroll
            for (int t = 0; t < 11; ++t) {
                float wt = gw.w[t];
                P0 = fmaf(wt, v[2 * t],     P0);
                Q0 = fmaf(wt, v[2 * t + 1], Q0);
                U0 = fmaf(wt, sqa[t],       U0);
                V0 = fmaf(wt, sqb[t],       V0);
                P1 = fmaf(wt, v[2 * t + 2], P1);
                Q1 = fmaf(wt, v[2 * t + 3], Q1);
                U1 = fmaf(wt, sqa[t + 1],   U1);
                V1 = fmaf(wt, sqb[t + 1],   V1);
            }
            hP[r][0] = P0; hQ[r][0] = Q0; hU[r][0] = U0; hV[r][0] = V0;
            hP[r][1] = P1; hQ[r][1] = Q1; hU[r][1] = U1; hV[r][1] = V1;
        }

        // ---- v-accumulate into pending rings ----
        #pragma unroll
        for (int c = 0; c < 2; ++c) {
            #pragma unroll
            for (int j = 0; j <= 10; ++j) {          // row 2k: w[10-j] -> slot j
                float wt = gw.w[10 - j];
                pendP[c][j] = fmaf(wt, hP[0][c], pendP[c][j]);
                pendQ[c][j] = fmaf(wt, hQ[0][c], pendQ[c][j]);
                pendU[c][j] = fmaf(wt, hU[0][c], pendU[c][j]);
                pendV[c][j] = fmaf(wt, hV[0][c], pendV[c][j]);
            }
            #pragma unroll
            for (int j = 1; j <= 11; ++j) {          // row 2k+1: w[11-j] -> slot j
                float wt = gw.w[11 - j];
                pendP[c][j] = fmaf(wt, hP[1][c], pendP[c][j]);
                pendQ[c][j] = fmaf(wt, hQ[1][c], pendQ[c][j]);
                pendU[c][j] = fmaf(wt, hU[1][c], pendU[c][j]);
                pendV[c][j] = fmaf(wt, hV[1][c], pendV[c][j]);
            }
        }

        // ---- emit 2 finished output rows x 2 cols (x2-rescaled, exact) ----
        #pragma unroll
        for (int e = 0; e < 2; ++e) {
            int rel = 2 * k - 10 + e;
            bool rowok = (unsigned)rel < (unsigned)rowsOut;
            #pragma unroll
            for (int c = 0; c < 2; ++c) {
                float p = pendP[c][e], q = pendQ[c][e];
                float uu = pendU[c][e], vv = pendV[c][e];
                float p2 = p * p, q2 = q * q;
                float A = p2 - q2;                       // 2*(2 mu12)
                float csn = (uu - vv - A) + C2x2;        // 2*(2 sigma12) + 2C2
                float csd = (uu + vv - p2 - q2) + C2x2;
                float cs  = csn * __builtin_amdgcn_rcpf(csd);
                float ss  = (A + C1x2) * __builtin_amdgcn_rcpf(p2 + q2 + C1x2) * cs;
                if (rowok && (c ? ok1 : ok0)) { ssum += ss; csum += cs; }
            }
        }

        // ---- shift rings by 2 slots ----
        #pragma unroll
        for (int c = 0; c < 2; ++c) {
            #pragma unroll
            for (int j = 0; j < 10; ++j) {
                pendP[c][j] = pendP[c][j + 2]; pendQ[c][j] = pendQ[c][j + 2];
                pendU[c][j] = pendU[c][j + 2]; pendV[c][j] = pendV[c][j + 2];
            }
            pendP[c][10] = 0.f; pendP[c][11] = 0.f;
            pendQ[c][10] = 0.f; pendQ[c][11] = 0.f;
            pendU[c][10] = 0.f; pendU[c][11] = 0.f;
            pendV[c][10] = 0.f; pendV[c][11] = 0.f;
        }

        // ---- 2x2 pool from registers: pooled col 64w+ln, always in range ----
        if (k < 32) {
            float sa = u0save[0].x + u0save[0].z + u0save[1].x + u0save[1].z;
            float sb = u0save[0].y + u0save[0].w + u0save[1].y + u0save[1].w;
            int prow = (oy0 >> 1) + k;
            size_t o = (size_t)ch * 256 * 256 + (size_t)prow * 256 + 64 * w + ln;
            p1x[o] = 0.125f * (sa + sb);
            p1y[o] = 0.125f * (sa - sb);
        }

        // ---- stage next rows (vmcnt drain after all compute; in-order DS) ----
        if (k + 1 < NIT) {
            write_slot(sl ^ 1);
            if (k + 2 < NIT) issue(oy0 + 2 * (k + 2));
        }
    }

    // ---- per-wave reduction + atomic accumulate (no barrier) ----
    for (int off = 32; off > 0; off >>= 1) {
        ssum += __shfl_down(ssum, off);
        csum += __shfl_down(csum, off);
    }
    if (ln == 0) {
        atomicAdd(&accum[ch], ssum);
        atomicAdd(&accum[96 + ch], csum);
    }
}

// ------------- tiny hierarchical pool: P1 -> P2, P3, P4 (r20 verbatim) -------------
__global__ __launch_bounds__(256)
void pool_pyramid_kernel(const float* __restrict__ p1x, const float* __restrict__ p1y,
                         float* __restrict__ p2x, float* __restrict__ p2y,
                         float* __restrict__ p3x, float* __restrict__ p3y,
                         float* __restrict__ p4x, float* __restrict__ p4y)
{
    const int tid  = threadIdx.x;
    const int ch   = blockIdx.y;
    const int tile = blockIdx.x;
    const int ty0 = (tile >> 2) * 64, tx0 = (tile & 3) * 64;
    const int tr = tid >> 4, tc = tid & 15;
    const int iy = ty0 + 4 * tr, ix = tx0 + 4 * tc;

    const float* X1 = p1x + (size_t)ch * 256 * 256;
    const float* Y1 = p1y + (size_t)ch * 256 * 256;

    float4 xr[4], yr[4];
    #pragma unroll
    for (int r = 0; r < 4; ++r) {
        xr[r] = *reinterpret_cast<const float4*>(X1 + (size_t)(iy + r) * 256 + ix);
        yr[r] = *reinterpret_cast<const float4*>(Y1 + (size_t)(iy + r) * 256 + ix);
    }

    float x200 = 0.25f * (xr[0].x + xr[0].y + xr[1].x + xr[1].y);
    float x201 = 0.25f * (xr[0].z + xr[0].w + xr[1].z + xr[1].w);
    float x210 = 0.25f * (xr[2].x + xr[2].y + xr[3].x + xr[3].y);
    float x211 = 0.25f * (xr[2].z + xr[2].w + xr[3].z + xr[3].w);
    float y200 = 0.25f * (yr[0].x + yr[0].y + yr[1].x + yr[1].y);
    float y201 = 0.25f * (yr[0].z + yr[0].w + yr[1].z + yr[1].w);
    float y210 = 0.25f * (yr[2].x + yr[2].y + yr[3].x + yr[3].y);
    float y211 = 0.25f * (yr[2].z + yr[2].w + yr[3].z + yr[3].w);
    {
        int oy = iy >> 1, ox = ix >> 1;
        float* bx = p2x + (size_t)ch * 128 * 128;
        float* by = p2y + (size_t)ch * 128 * 128;
        *reinterpret_cast<float2*>(bx + (size_t)oy * 128 + ox)       = make_float2(x200, x201);
        *reinterpret_cast<float2*>(bx + (size_t)(oy + 1) * 128 + ox) = make_float2(x210, x211);
        *reinterpret_cast<float2*>(by + (size_t)oy * 128 + ox)       = make_float2(y200, y201);
        *reinterpret_cast<float2*>(by + (size_t)(oy + 1) * 128 + ox) = make_float2(y210, y211);
    }

    float x3 = 0.25f * (x200 + x201 + x210 + x211);
    float y3 = 0.25f * (y200 + y201 + y210 + y211);
    p3x[(size_t)ch * 64 * 64 + (size_t)(iy >> 2) * 64 + (ix >> 2)] = x3;
    p3y[(size_t)ch * 64 * 64 + (size_t)(iy >> 2) * 64 + (ix >> 2)] = y3;

    float x4 = x3 + __shfl_xor(x3, 1);
    float y4 = y3 + __shfl_xor(y3, 1);
    x4 += __shfl_xor(x4, 16);
    y4 += __shfl_xor(y4, 16);
    if (((tr | tc) & 1) == 0) {
        p4x[(size_t)ch * 32 * 32 + (size_t)(iy >> 3) * 32 + (ix >> 3)] = 0.25f * x4;
        p4y[(size_t)ch * 32 * 32 + (size_t)(iy >> 3) * 32 + (ix >> 3)] = 0.25f * y4;
    }
}

// ------------- Fused levels 1..4 kernel (r20 verbatim, 630 blocks) -------------
__global__ __launch_bounds__(256)
void ssim_rest_kernel(const float* __restrict__ x1, const float* __restrict__ y1,
                      const float* __restrict__ x2, const float* __restrict__ y2,
                      const float* __restrict__ x3, const float* __restrict__ y3,
                      const float* __restrict__ x4, const float* __restrict__ y4,
                      float* __restrict__ accum, GWin gw)
{
    __shared__ float4 ab[2][2][264];

    const int bid = blockIdx.x;
    const int L = (bid >= 624) ? 3 : (bid >= 576) ? 2 : (bid >= 384) ? 1 : 0;
    const int off0 = (L == 0) ? 0 : (L == 1) ? 384 : (L == 2) ? 576 : 624;
    const int r = bid - off0;

    const int S      = (L == 0) ? 256 : (L == 1) ? 128 : (L == 2) ? 64 : 32;
    const int outS   = (L == 0) ? 246 : (L == 1) ? 118 : (L == 2) ? 54 : 22;
    const int rps    = (L == 0) ? 32  : (L == 1) ? 16  : (L == 2) ? 16 : 22;
    const int tpcLog = (L == 0) ? 7   : (L == 1) ? 6   : (L == 2) ? 5  : 4;
    const int stripsLog = (L == 0) ? 3 : (L == 1) ? 3 : (L == 2) ? 2 : 0;
    const float* Xl = (L == 0) ? x1 : (L == 1) ? x2 : (L == 2) ? x3 : x4;
    const float* Yl = (L == 0) ? y1 : (L == 1) ? y2 : (L == 2) ? y3 : y4;
    float* acc = accum + 192 * (L + 1);

    const int zidx  = r >> stripsLog;
    const int strip = r & ((1 << stripsLog) - 1);

    const int tid = threadIdx.x;
    const int tpc = 1 << tpcLog;
    const int lt  = tid & (tpc - 1);
    const int sub = tid >> tpcLog;
    const int ch  = zidx * (256 >> tpcLog) + sub;
    const int oy0 = strip * rps;
    const int gc  = 2 * lt;

    int rowsOut = outS - oy0; if (rowsOut > rps) rowsOut = rps;
    const int NIT = (rowsOut + 11) >> 1;

    const float* Xc = Xl + (size_t)ch * S * S;
    const float* Yc = Yl + (size_t)ch * S * S;

    float2 sx0, sy0, sx1, sy1;

    auto issue = [&](int baseRow) {
        int gr0 = baseRow;     if (gr0 > S - 1) gr0 = S - 1;
        int gr1 = baseRow + 1; if (gr1 > S - 1) gr1 = S - 1;
        sx0 = *reinterpret_cast<const float2*>(Xc + (size_t)gr0 * S + gc);
        sy0 = *reinterpret_cast<const float2*>(Yc + (size_t)gr0 * S + gc);
        sx1 = *reinterpret_cast<const float2*>(Xc + (size_t)gr1 * S + gc);
        sy1 = *reinterpret_cast<const float2*>(Yc + (size_t)gr1 * S + gc);
    };
    auto write_slot = [&](int sl) {
        ab[sl][0][tid] = make_float4(sx0.x + sy0.x, sx0.x - sy0.x,
                                     sx0.y + sy0.y, sx0.y - sy0.y);
        ab[sl][1][tid] = make_float4(sx1.x + sy1.x, sx1.x - sy1.x,
                                     sx1.y + sy1.y, sx1.y - sy1.y);
    };

    float pendP[2][12], pendQ[2][12], pendU[2][12], pendV[2][12];
    #pragma unroll
    for (int c = 0; c < 2; ++c)
        #pragma unroll
        for (int j = 0; j < 12; ++j) { pendP[c][j] = 0.f; pendQ[c][j] = 0.f; pendU[c][j] = 0.f; pendV[c][j] = 0.f; }

    float ssum = 0.f, csum = 0.f;
    const float C1x2 = 2e-4f, C2x2 = 1.8e-3f;
    const bool ok0 = gc < outS, ok1 = (gc + 1) < outS;

    if (tid < 8) {
        float4 z = make_float4(0.f, 0.f, 0.f, 0.f);
        ab[0][0][256 + tid] = z; ab[0][1][256 + tid] = z;
        ab[1][0][256 + tid] = z; ab[1][1][256 + tid] = z;
    }
    issue(oy0);
    write_slot(0);
    issue(oy0 + 2);
    __syncthreads();

    for (int k = 0; k < NIT; ++k) {
        const int sl = k & 1;

        float hP[2][2], hQ[2][2], hU[2][2], hV[2][2];
        #pragma unroll
        for (int r2 = 0; r2 < 2; ++r2) {
            const float4* bp = &ab[sl][r2][tid];
            float4 u[6];
            #pragma unroll
            for (int i = 0; i < 6; ++i) u[i] = bp[i];
            const float* v = reinterpret_cast<const float*>(u);
            float sqa[12], sqb[12];
            #pragma unroll
            for (int j = 0; j < 12; ++j) {
                float a = v[2 * j], b = v[2 * j + 1];
                sqa[j] = a * a; sqb[j] = b * b;
            }
            float P0 = 0.f, Q0 = 0.f, U0 = 0.f, V0 = 0.f;
            float P1 = 0.f, Q1 = 0.f, U1 = 0.f, V1 = 0.f;
            #pragma unroll
            for (int t = 0; t < 11; ++t) {
                float wt = gw.w[t];
                P0 = fmaf(wt, v[2 * t],     P0);
                Q0 = fmaf(wt, v[2 * t + 1], Q0);
                U0 = fmaf(wt, sqa[t],       U0);
                V0 = fmaf(wt, sqb[t],       V0);
                P1 = fmaf(wt, v[2 * t + 2], P1);
                Q1 = fmaf(wt, v[2 * t + 3], Q1);
                U1 = fmaf(wt, sqa[t + 1],   U1);
                V1 = fmaf(wt, sqb[t + 1],   V1);
            }
            hP[r2][0] = P0; hQ[r2][0] = Q0; hU[r2][0] = U0; hV[r2][0] = V0;
            hP[r2][1] = P1; hQ[r2][1] = Q1; hU[r2][1] = U1; hV[r2][1] = V1;
        }

        #pragma unroll
        for (int c = 0; c < 2; ++c) {
            #pragma unroll
            for (int j = 0; j <= 10; ++j) {
                float wt = gw.w[10 - j];
                pendP[c][j] = fmaf(wt, hP[0][c], pendP[c][j]);
                pendQ[c][j] = fmaf(wt, hQ[0][c], pendQ[c][j]);
                pendU[c][j] = fmaf(wt, hU[0][c], pendU[c][j]);
                pendV[c][j] = fmaf(wt, hV[0][c], pendV[c][j]);
            }
            #pragma unroll
            for (int j = 1; j <= 11; ++j) {
                float wt = gw.w[11 - j];
                pendP[c][j] = fmaf(wt, hP[1][c], pendP[c][j]);
                pendQ[c][j] = fmaf(wt, hQ[1][c], pendQ[c][j]);
                pendU[c][j] = fmaf(wt, hU[1][c], pendU[c][j]);
                pendV[c][j] = fmaf(wt, hV[1][c], pendV[c][j]);
            }
        }

        #pragma unroll
        for (int e = 0; e < 2; ++e) {
            int rel = 2 * k - 10 + e;
            bool rowok = (unsigned)rel < (unsigned)rowsOut;
            #pragma unroll
            for (int c = 0; c < 2; ++c) {
                float p = pendP[c][e], q = pendQ[c][e];
                float uu = pendU[c][e], vv = pendV[c][e];
                float p2 = p * p, q2 = q * q;
                float A = p2 - q2;
                float csn = (uu - vv - A) + C2x2;
                float csd = (uu + vv - p2 - q2) + C2x2;
                float cs  = csn * __builtin_amdgcn_rcpf(csd);
                float ss  = (A + C1x2) * __builtin_amdgcn_rcpf(p2 + q2 + C1x2) * cs;
                if (rowok && (c ? ok1 : ok0)) { ssum += ss; csum += cs; }
            }
        }

        #pragma unroll
        for (int c = 0; c < 2; ++c) {
            #pragma unroll
            for (int j = 0; j < 10; ++j) {
                pendP[c][j] = pendP[c][j + 2]; pendQ[c][j] = pendQ[c][j + 2];
                pendU[c][j] = pendU[c][j + 2]; pendV[c][j] = pendV[c][j + 2];
            }
            pendP[c][10] = 0.f; pendP[c][11] = 0.f;
            pendQ[c][10] = 0.f; pendQ[c][11] = 0.f;
            pendU[c][10] = 0.f; pendU[c][11] = 0.f;
            pendV[c][10] = 0.f; pendV[c][11] = 0.f;
        }

        if (k + 1 < NIT) {
            write_slot(sl ^ 1);
            if (k + 2 < NIT) issue(oy0 + 2 * (k + 2));
        }
        __syncthreads();
    }

    {
        int rw = (tpc < 64) ? tpc : 64;
        for (int off = rw >> 1; off > 0; off >>= 1) {
            ssum += __shfl_down(ssum, off);
            csum += __shfl_down(csum, off);
        }
        if ((lt & 63) == 0) {
            atomicAdd(&acc[ch], ssum);
            atomicAdd(&acc[96 + ch], csum);
        }
    }
}

__global__ void finalize_kernel(const float* __restrict__ accum, float* __restrict__ out)
{
    __shared__ float red[2];
    const int t = threadIdx.x;   // 128 threads
    const float w[5]   = {0.0448f, 0.2856f, 0.3001f, 0.2363f, 0.1333f};
    const float inv[5] = {1.f / (502.f * 502.f), 1.f / (246.f * 246.f),
                          1.f / (118.f * 118.f), 1.f / (54.f * 54.f),
                          1.f / (22.f * 22.f)};
    float ms = 0.f;
    if (t < 96) {
        ms = 1.f;
        #pragma unroll
        for (int l = 0; l < 5; ++l) {
            float v = (l < 4) ? accum[l * 192 + 96 + t] : accum[l * 192 + t];
            v *= inv[l];
            v = fmaxf(v, 0.f);
            ms *= powf(v, w[l]);
        }
    }
    for (int off = 32; off > 0; off >>= 1) ms += __shfl_down(ms, off);
    int wid = t >> 6, lane = t & 63;
    if (lane == 0) red[wid] = ms;
    __syncthreads();
    if (t == 0) out[0] = 1.f - (red[0] + red[1]) * (1.f / 96.f);
}

extern "C" void kernel_launch(void* const* d_in, const int* in_sizes, int n_in,
                              void* d_out, int out_size, void* d_ws, size_t ws_size,
                              hipStream_t stream)
{
    (void)in_sizes; (void)n_in; (void)out_size; (void)ws_size;
    const float* X = (const float*)d_in[0];
    const float* Y = (const float*)d_in[1];
    float* out = (float*)d_out;
    float* ws  = (float*)d_ws;

    // Gaussian window (size 11, sigma 1.5), normalized
    GWin gw;
    {
        double g[11], s = 0.0;
        for (int i = 0; i < 11; ++i) { double d = i - 5; g[i] = exp(-(d * d) / 4.5); s += g[i]; }
        for (int i = 0; i < 11; ++i) gw.w[i] = (float)(g[i] / s);
    }

    // workspace layout (floats): accum then pyramid buffers
    float* accum = ws;                 // L0 at +0, L1..L4 at +192*(L+1)
    size_t off = 1024;
    float* p1x = ws + off; off += (size_t)96 * 256 * 256;
    float* p1y = ws + off; off += (size_t)96 * 256 * 256;
    float* p2x = ws + off; off += (size_t)96 * 128 * 128;
    float* p2y = ws + off; off += (size_t)96 * 128 * 128;
    float* p3x = ws + off; off += (size_t)96 * 64 * 64;
    float* p3y = ws + off; off += (size_t)96 * 64 * 64;
    float* p4x = ws + off; off += (size_t)96 * 32 * 32;
    float* p4y = ws + off; off += (size_t)96 * 32 * 32;

    hipMemsetAsync(accum, 0, 5 * 192 * sizeof(float), stream);

    // L0: barrier-free wave-band kernel (writes P1), 8 strips x 96 channels
    ssim_l0_kernel<<<dim3(8, 1, 96), 256, 0, stream>>>(
        X, Y, p1x, p1y, accum, gw);

    // P1 -> P2, P3, P4 (hierarchical, shfl butterflies)
    pool_pyramid_kernel<<<dim3(16, 96), 256, 0, stream>>>(
        p1x, p1y, p2x, p2y, p3x, p3y, p4x, p4y);

    // L1..L4 fused: 384 + 192 + 48 + 6 = 630 blocks
    ssim_rest_kernel<<<dim3(630), 256, 0, stream>>>(
        p1x, p1y, p2x, p2y, p3x, p3y, p4x, p4y, accum, gw);

    finalize_kernel<<<1, 128, 0, stream>>>(accum, out);
}

// Round 23
// 150.696 us; speedup vs baseline: 1.0523x; 1.0408x over previous
//
#include <hip/hip_runtime.h>
#include <math.h>

// MS-SSIM loss, 5 levels, 11-tap separable Gaussian (sigma=1.5), VALID padding.
// FINAL (r20, best measured 149.7us): pipeline = L0 (r15 row-streaming body,
// 84 VGPR, DS-halved col-pair layout, writes P1) -> pool_pyramid (P1->P2,P3,P4)
// -> fused rest kernel (L1..L4 concurrent, 630 blocks) -> finalize.
// 4-map transform (a=x+y, b=x-y -> P,Q,U,V), x2-rescaled emit algebra (exact).

struct GWin { float w[11]; };

// ---------------- r15 row-streaming SSIM kernel (L0 only here) ----------------
__global__ __launch_bounds__(256)
void ssim_rows_kernel(const float* __restrict__ X, const float* __restrict__ Y,
                      float* __restrict__ poolX, float* __restrict__ poolY,
                      float* __restrict__ accum,   // [0..95]=ssim, [96..191]=cs
                      int S, int outS, int doPool, int rps, int tpcLog, GWin gw)
{
    __shared__ float4 ab[2][2][264];     // [slot][row01][col-pair unit {a,b,a,b}]

    const int tid = threadIdx.x;
    const int tpc = 1 << tpcLog;         // threads per channel = S/2
    const int lt  = tid & (tpc - 1);
    const int sub = tid >> tpcLog;
    const int ch  = blockIdx.z * (256 >> tpcLog) + sub;
    const int oy0 = blockIdx.x * rps;
    const int halfS = S >> 1;
    const int gc  = 2 * lt;              // thread's base input/output column

    int rowsOut = outS - oy0; if (rowsOut > rps) rowsOut = rps;
    const int NIT = (rowsOut + 11) >> 1; // iterations (2 input rows each)

    const float* Xc = X + (size_t)ch * S * S;
    const float* Yc = Y + (size_t)ch * S * S;

    float2 sx0, sy0, sx1, sy1;           // prefetched global data (2 rows)

    auto issue = [&](int baseRow) {
        int gr0 = baseRow;     if (gr0 > S - 1) gr0 = S - 1;
        int gr1 = baseRow + 1; if (gr1 > S - 1) gr1 = S - 1;
        sx0 = *reinterpret_cast<const float2*>(Xc + (size_t)gr0 * S + gc);
        sy0 = *reinterpret_cast<const float2*>(Yc + (size_t)gr0 * S + gc);
        sx1 = *reinterpret_cast<const float2*>(Xc + (size_t)gr1 * S + gc);
        sy1 = *reinterpret_cast<const float2*>(Yc + (size_t)gr1 * S + gc);
    };
    auto write_slot = [&](int sl) {      // one b128 per row: {a0,b0,a1,b1}
        ab[sl][0][tid] = make_float4(sx0.x + sy0.x, sx0.x - sy0.x,
                                     sx0.y + sy0.y, sx0.y - sy0.y);
        ab[sl][1][tid] = make_float4(sx1.x + sy1.x, sx1.x - sy1.x,
                                     sx1.y + sy1.y, sx1.y - sy1.y);
    };

    // pending v-conv partials: [col][slot], all static-indexed
    float pendP[2][12], pendQ[2][12], pendU[2][12], pendV[2][12];
    #pragma unroll
    for (int c = 0; c < 2; ++c)
        #pragma unroll
        for (int j = 0; j < 12; ++j) { pendP[c][j] = 0.f; pendQ[c][j] = 0.f; pendU[c][j] = 0.f; pendV[c][j] = 0.f; }

    float ssum = 0.f, csum = 0.f;
    const float C1x2 = 2e-4f, C2x2 = 1.8e-3f;
    const bool ok0 = (gc    ) < outS;
    const bool ok1 = (gc + 1) < outS;

    // prologue (zero the 8 overrun units read by the last threads)
    if (tid < 8) {
        float4 z = make_float4(0.f, 0.f, 0.f, 0.f);
        ab[0][0][256 + tid] = z; ab[0][1][256 + tid] = z;
        ab[1][0][256 + tid] = z; ab[1][1][256 + tid] = z;
    }
    issue(oy0);
    write_slot(0);
    issue(oy0 + 2);
    __syncthreads();

    for (int k = 0; k < NIT; ++k) {
        const int sl = k & 1;

        // ---- h-conv for both staged rows: 6 ds_read_b128 per row ----
        float hP[2][2], hQ[2][2], hU[2][2], hV[2][2];   // [row][col]
        float4 u0save[2];
        #pragma unroll
        for (int r = 0; r < 2; ++r) {
            const float4* bp = &ab[sl][r][tid];
            float4 u[6];
            #pragma unroll
            for (int i = 0; i < 6; ++i) u[i] = bp[i];
            u0save[r] = u[0];
            const float* v = reinterpret_cast<const float*>(u);  // v[2j]=a_j, v[2j+1]=b_j
            float sqa[12], sqb[12];
            #pragma unroll
            for (int j = 0; j < 12; ++j) {
                float a = v[2 * j], b = v[2 * j + 1];
                sqa[j] = a * a; sqb[j] = b * b;
            }
            float P0 = 0.f, Q0 = 0.f, U0 = 0.f, V0 = 0.f;
            float P1 = 0.f, Q1 = 0.f, U1 = 0.f, V1 = 0.f;
            #pragma unroll
            for (int t = 0; t < 11; ++t) {
                float wt = gw.w[t];
                P0 = fmaf(wt, v[2 * t],     P0);
                Q0 = fmaf(wt, v[2 * t + 1], Q0);
                U0 = fmaf(wt, sqa[t],       U0);
                V0 = fmaf(wt, sqb[t],       V0);
                P1 = fmaf(wt, v[2 * t + 2], P1);
                Q1 = fmaf(wt, v[2 * t + 3], Q1);
                U1 = fmaf(wt, sqa[t + 1],   U1);
                V1 = fmaf(wt, sqb[t + 1],   V1);
            }
            hP[r][0] = P0; hQ[r][0] = Q0; hU[r][0] = U0; hV[r][0] = V0;
            hP[r][1] = P1; hQ[r][1] = Q1; hU[r][1] = U1; hV[r][1] = V1;
        }

        // ---- v-accumulate into pending rings ----
        #pragma unroll
        for (int c = 0; c < 2; ++c) {
            #pragma unroll
            for (int j = 0; j <= 10; ++j) {          // row 2k: w[10-j] -> slot j
                float wt = gw.w[10 - j];
                pendP[c][j] = fmaf(wt, hP[0][c], pendP[c][j]);
                pendQ[c][j] = fmaf(wt, hQ[0][c], pendQ[c][j]);
                pendU[c][j] = fmaf(wt, hU[0][c], pendU[c][j]);
                pendV[c][j] = fmaf(wt, hV[0][c], pendV[c][j]);
            }
            #pragma unroll
            for (int j = 1; j <= 11; ++j) {          // row 2k+1: w[11-j] -> slot j
                float wt = gw.w[11 - j];
                pendP[c][j] = fmaf(wt, hP[1][c], pendP[c][j]);
                pendQ[c][j] = fmaf(wt, hQ[1][c], pendQ[c][j]);
                pendU[c][j] = fmaf(wt, hU[1][c], pendU[c][j]);
                pendV[c][j] = fmaf(wt, hV[1][c], pendV[c][j]);
            }
        }

        // ---- emit 2 finished output rows x 2 cols (x2-rescaled, exact) ----
        #pragma unroll
        for (int e = 0; e < 2; ++e) {
            int rel = 2 * k - 10 + e;
            bool rowok = (unsigned)rel < (unsigned)rowsOut;
            #pragma unroll
            for (int c = 0; c < 2; ++c) {
                float p = pendP[c][e], q = pendQ[c][e];
                float uu = pendU[c][e], vv = pendV[c][e];
                float p2 = p * p, q2 = q * q;
                float A = p2 - q2;                       // 2*(2 mu12)
                float csn = (uu - vv - A) + C2x2;        // 2*(2 sigma12) + 2C2
                float csd = (uu + vv - p2 - q2) + C2x2;
                float cs  = csn * __builtin_amdgcn_rcpf(csd);
                float ss  = (A + C1x2) * __builtin_amdgcn_rcpf(p2 + q2 + C1x2) * cs;
                if (rowok && (c ? ok1 : ok0)) { ssum += ss; csum += cs; }
            }
        }

        // ---- shift rings by 2 slots ----
        #pragma unroll
        for (int c = 0; c < 2; ++c) {
            #pragma unroll
            for (int j = 0; j < 10; ++j) {
                pendP[c][j] = pendP[c][j + 2]; pendQ[c][j] = pendQ[c][j + 2];
                pendU[c][j] = pendU[c][j + 2]; pendV[c][j] = pendV[c][j + 2];
            }
            pendP[c][10] = 0.f; pendP[c][11] = 0.f;
            pendQ[c][10] = 0.f; pendQ[c][11] = 0.f;
            pendU[c][10] = 0.f; pendU[c][11] = 0.f;
            pendV[c][10] = 0.f; pendV[c][11] = 0.f;
        }

        // ---- 2x2 pool from registers (thread's col pair = 1 pooled output) ----
        if (doPool && k < (rps >> 1)) {
            float sa = u0save[0].x + u0save[0].z + u0save[1].x + u0save[1].z;
            float sb = u0save[0].y + u0save[0].w + u0save[1].y + u0save[1].w;
            int prow = (oy0 >> 1) + k;
            size_t o = (size_t)ch * halfS * halfS + (size_t)prow * halfS + lt;
            poolX[o] = 0.125f * (sa + sb);
            poolY[o] = 0.125f * (sa - sb);
        }

        // ---- stage next rows (vmcnt drain lives here, after all compute) ----
        if (k + 1 < NIT) {
            write_slot(sl ^ 1);
            if (k + 2 < NIT) issue(oy0 + 2 * (k + 2));
        }
        __syncthreads();
    }

    // ---- per-channel-subgroup reduction + atomic accumulate ----
    {
        int rw = (tpc < 64) ? tpc : 64;
        for (int off = rw >> 1; off > 0; off >>= 1) {
            ssum += __shfl_down(ssum, off);
            csum += __shfl_down(csum, off);
        }
        if ((lt & 63) == 0) {
            atomicAdd(&accum[ch], ssum);
            atomicAdd(&accum[96 + ch], csum);
        }
    }
}

// ------------- tiny hierarchical pool: P1 -> P2, P3, P4 -------------
__global__ __launch_bounds__(256)
void pool_pyramid_kernel(const float* __restrict__ p1x, const float* __restrict__ p1y,
                         float* __restrict__ p2x, float* __restrict__ p2y,
                         float* __restrict__ p3x, float* __restrict__ p3y,
                         float* __restrict__ p4x, float* __restrict__ p4y)
{
    const int tid  = threadIdx.x;
    const int ch   = blockIdx.y;                 // 96
    const int tile = blockIdx.x;                 // 16 tiles of 64x64 in 256x256
    const int ty0 = (tile >> 2) * 64, tx0 = (tile & 3) * 64;
    const int tr = tid >> 4, tc = tid & 15;      // 16x16 threads, each 4x4 input
    const int iy = ty0 + 4 * tr, ix = tx0 + 4 * tc;

    const float* X1 = p1x + (size_t)ch * 256 * 256;
    const float* Y1 = p1y + (size_t)ch * 256 * 256;

    float4 xr[4], yr[4];
    #pragma unroll
    for (int r = 0; r < 4; ++r) {
        xr[r] = *reinterpret_cast<const float4*>(X1 + (size_t)(iy + r) * 256 + ix);
        yr[r] = *reinterpret_cast<const float4*>(Y1 + (size_t)(iy + r) * 256 + ix);
    }

    // P2 (128x128): 2x2 outputs per thread
    float x200 = 0.25f * (xr[0].x + xr[0].y + xr[1].x + xr[1].y);
    float x201 = 0.25f * (xr[0].z + xr[0].w + xr[1].z + xr[1].w);
    float x210 = 0.25f * (xr[2].x + xr[2].y + xr[3].x + xr[3].y);
    float x211 = 0.25f * (xr[2].z + xr[2].w + xr[3].z + xr[3].w);
    float y200 = 0.25f * (yr[0].x + yr[0].y + yr[1].x + yr[1].y);
    float y201 = 0.25f * (yr[0].z + yr[0].w + yr[1].z + yr[1].w);
    float y210 = 0.25f * (yr[2].x + yr[2].y + yr[3].x + yr[3].y);
    float y211 = 0.25f * (yr[2].z + yr[2].w + yr[3].z + yr[3].w);
    {
        int oy = iy >> 1, ox = ix >> 1;
        float* bx = p2x + (size_t)ch * 128 * 128;
        float* by = p2y + (size_t)ch * 128 * 128;
        *reinterpret_cast<float2*>(bx + (size_t)oy * 128 + ox)       = make_float2(x200, x201);
        *reinterpret_cast<float2*>(bx + (size_t)(oy + 1) * 128 + ox) = make_float2(x210, x211);
        *reinterpret_cast<float2*>(by + (size_t)oy * 128 + ox)       = make_float2(y200, y201);
        *reinterpret_cast<float2*>(by + (size_t)(oy + 1) * 128 + ox) = make_float2(y210, y211);
    }

    // P3 (64x64): one output per thread
    float x3 = 0.25f * (x200 + x201 + x210 + x211);
    float y3 = 0.25f * (y200 + y201 + y210 + y211);
    p3x[(size_t)ch * 64 * 64 + (size_t)(iy >> 2) * 64 + (ix >> 2)] = x3;
    p3y[(size_t)ch * 64 * 64 + (size_t)(iy >> 2) * 64 + (ix >> 2)] = y3;

    // P4 (32x32): butterfly across tc (xor 1) and tr (xor 16)
    float x4 = x3 + __shfl_xor(x3, 1);
    float y4 = y3 + __shfl_xor(y3, 1);
    x4 += __shfl_xor(x4, 16);
    y4 += __shfl_xor(y4, 16);
    if (((tr | tc) & 1) == 0) {
        p4x[(size_t)ch * 32 * 32 + (size_t)(iy >> 3) * 32 + (ix >> 3)] = 0.25f * x4;
        p4y[(size_t)ch * 32 * 32 + (size_t)(iy >> 3) * 32 + (ix >> 3)] = 0.25f * y4;
    }
}

// ------------- Fused levels 1..4 kernel (no pooling, 630 blocks) -------------
__global__ __launch_bounds__(256)
void ssim_rest_kernel(const float* __restrict__ x1, const float* __restrict__ y1,
                      const float* __restrict__ x2, const float* __restrict__ y2,
                      const float* __restrict__ x3, const float* __restrict__ y3,
                      const float* __restrict__ x4, const float* __restrict__ y4,
                      float* __restrict__ accum, GWin gw)
{
    __shared__ float4 ab[2][2][264];

    const int bid = blockIdx.x;
    const int L = (bid >= 624) ? 3 : (bid >= 576) ? 2 : (bid >= 384) ? 1 : 0;
    const int off0 = (L == 0) ? 0 : (L == 1) ? 384 : (L == 2) ? 576 : 624;
    const int r = bid - off0;

    const int S      = (L == 0) ? 256 : (L == 1) ? 128 : (L == 2) ? 64 : 32;
    const int outS   = (L == 0) ? 246 : (L == 1) ? 118 : (L == 2) ? 54 : 22;
    const int rps    = (L == 0) ? 32  : (L == 1) ? 16  : (L == 2) ? 16 : 22;
    const int tpcLog = (L == 0) ? 7   : (L == 1) ? 6   : (L == 2) ? 5  : 4;
    const int stripsLog = (L == 0) ? 3 : (L == 1) ? 3 : (L == 2) ? 2 : 0;
    const float* Xl = (L == 0) ? x1 : (L == 1) ? x2 : (L == 2) ? x3 : x4;
    const float* Yl = (L == 0) ? y1 : (L == 1) ? y2 : (L == 2) ? y3 : y4;
    float* acc = accum + 192 * (L + 1);

    const int zidx  = r >> stripsLog;
    const int strip = r & ((1 << stripsLog) - 1);

    const int tid = threadIdx.x;
    const int tpc = 1 << tpcLog;
    const int lt  = tid & (tpc - 1);
    const int sub = tid >> tpcLog;
    const int ch  = zidx * (256 >> tpcLog) + sub;
    const int oy0 = strip * rps;
    const int gc  = 2 * lt;

    int rowsOut = outS - oy0; if (rowsOut > rps) rowsOut = rps;
    const int NIT = (rowsOut + 11) >> 1;

    const float* Xc = Xl + (size_t)ch * S * S;
    const float* Yc = Yl + (size_t)ch * S * S;

    float2 sx0, sy0, sx1, sy1;

    auto issue = [&](int baseRow) {
        int gr0 = baseRow;     if (gr0 > S - 1) gr0 = S - 1;
        int gr1 = baseRow + 1; if (gr1 > S - 1) gr1 = S - 1;
        sx0 = *reinterpret_cast<const float2*>(Xc + (size_t)gr0 * S + gc);
        sy0 = *reinterpret_cast<const float2*>(Yc + (size_t)gr0 * S + gc);
        sx1 = *reinterpret_cast<const float2*>(Xc + (size_t)gr1 * S + gc);
        sy1 = *reinterpret_cast<const float2*>(Yc + (size_t)gr1 * S + gc);
    };
    auto write_slot = [&](int sl) {
        ab[sl][0][tid] = make_float4(sx0.x + sy0.x, sx0.x - sy0.x,
                                     sx0.y + sy0.y, sx0.y - sy0.y);
        ab[sl][1][tid] = make_float4(sx1.x + sy1.x, sx1.x - sy1.x,
                                     sx1.y + sy1.y, sx1.y - sy1.y);
    };

    float pendP[2][12], pendQ[2][12], pendU[2][12], pendV[2][12];
    #pragma unroll
    for (int c = 0; c < 2; ++c)
        #pragma unroll
        for (int j = 0; j < 12; ++j) { pendP[c][j] = 0.f; pendQ[c][j] = 0.f; pendU[c][j] = 0.f; pendV[c][j] = 0.f; }

    float ssum = 0.f, csum = 0.f;
    const float C1x2 = 2e-4f, C2x2 = 1.8e-3f;
    const bool ok0 = gc < outS, ok1 = (gc + 1) < outS;

    if (tid < 8) {
        float4 z = make_float4(0.f, 0.f, 0.f, 0.f);
        ab[0][0][256 + tid] = z; ab[0][1][256 + tid] = z;
        ab[1][0][256 + tid] = z; ab[1][1][256 + tid] = z;
    }
    issue(oy0);
    write_slot(0);
    issue(oy0 + 2);
    __syncthreads();

    for (int k = 0; k < NIT; ++k) {
        const int sl = k & 1;

        float hP[2][2], hQ[2][2], hU[2][2], hV[2][2];
        #pragma unroll
        for (int r2 = 0; r2 < 2; ++r2) {
            const float4* bp = &ab[sl][r2][tid];
            float4 u[6];
            #pragma unroll
            for (int i = 0; i < 6; ++i) u[i] = bp[i];
            const float* v = reinterpret_cast<const float*>(u);
            float sqa[12], sqb[12];
            #pragma unroll
            for (int j = 0; j < 12; ++j) {
                float a = v[2 * j], b = v[2 * j + 1];
                sqa[j] = a * a; sqb[j] = b * b;
            }
            float P0 = 0.f, Q0 = 0.f, U0 = 0.f, V0 = 0.f;
            float P1 = 0.f, Q1 = 0.f, U1 = 0.f, V1 = 0.f;
            #pragma unroll
            for (int t = 0; t < 11; ++t) {
                float wt = gw.w[t];
                P0 = fmaf(wt, v[2 * t],     P0);
                Q0 = fmaf(wt, v[2 * t + 1], Q0);
                U0 = fmaf(wt, sqa[t],       U0);
                V0 = fmaf(wt, sqb[t],       V0);
                P1 = fmaf(wt, v[2 * t + 2], P1);
                Q1 = fmaf(wt, v[2 * t + 3], Q1);
                U1 = fmaf(wt, sqa[t + 1],   U1);
                V1 = fmaf(wt, sqb[t + 1],   V1);
            }
            hP[r2][0] = P0; hQ[r2][0] = Q0; hU[r2][0] = U0; hV[r2][0] = V0;
            hP[r2][1] = P1; hQ[r2][1] = Q1; hU[r2][1] = U1; hV[r2][1] = V1;
        }

        #pragma unroll
        for (int c = 0; c < 2; ++c) {
            #pragma unroll
            for (int j = 0; j <= 10; ++j) {
                float wt = gw.w[10 - j];
                pendP[c][j] = fmaf(wt, hP[0][c], pendP[c][j]);
                pendQ[c][j] = fmaf(wt, hQ[0][c], pendQ[c][j]);
                pendU[c][j] = fmaf(wt, hU[0][c], pendU[c][j]);
                pendV[c][j] = fmaf(wt, hV[0][c], pendV[c][j]);
            }
            #pragma unroll
            for (int j = 1; j <= 11; ++j) {
                float wt = gw.w[11 - j];
                pendP[c][j] = fmaf(wt, hP[1][c], pendP[c][j]);
                pendQ[c][j] = fmaf(wt, hQ[1][c], pendQ[c][j]);
                pendU[c][j] = fmaf(wt, hU[1][c], pendU[c][j]);
                pendV[c][j] = fmaf(wt, hV[1][c], pendV[c][j]);
            }
        }

        #pragma unroll
        for (int e = 0; e < 2; ++e) {
            int rel = 2 * k - 10 + e;
            bool rowok = (unsigned)rel < (unsigned)rowsOut;
            #pragma unroll
            for (int c = 0; c < 2; ++c) {
                float p = pendP[c][e], q = pendQ[c][e];
                float uu = pendU[c][e], vv = pendV[c][e];
                float p2 = p * p, q2 = q * q;
                float A = p2 - q2;
                float csn = (uu - vv - A) + C2x2;
                float csd = (uu + vv - p2 - q2) + C2x2;
                float cs  = csn * __builtin_amdgcn_rcpf(csd);
                float ss  = (A + C1x2) * __builtin_amdgcn_rcpf(p2 + q2 + C1x2) * cs;
                if (rowok && (c ? ok1 : ok0)) { ssum += ss; csum += cs; }
            }
        }

        #pragma unroll
        for (int c = 0; c < 2; ++c) {
            #pragma unroll
            for (int j = 0; j < 10; ++j) {
                pendP[c][j] = pendP[c][j + 2]; pendQ[c][j] = pendQ[c][j + 2];
                pendU[c][j] = pendU[c][j + 2]; pendV[c][j] = pendV[c][j + 2];
            }
            pendP[c][10] = 0.f; pendP[c][11] = 0.f;
            pendQ[c][10] = 0.f; pendQ[c][11] = 0.f;
            pendU[c][10] = 0.f; pendU[c][11] = 0.f;
            pendV[c][10] = 0.f; pendV[c][11] = 0.f;
        }

        if (k + 1 < NIT) {
            write_slot(sl ^ 1);
            if (k + 2 < NIT) issue(oy0 + 2 * (k + 2));
        }
        __syncthreads();
    }

    {
        int rw = (tpc < 64) ? tpc : 64;
        for (int off = rw >> 1; off > 0; off >>= 1) {
            ssum += __shfl_down(ssum, off);
            csum += __shfl_down(csum, off);
        }
        if ((lt & 63) == 0) {
            atomicAdd(&acc[ch], ssum);
            atomicAdd(&acc[96 + ch], csum);
        }
    }
}

__global__ void finalize_kernel(const float* __restrict__ accum, float* __restrict__ out)
{
    __shared__ float red[2];
    const int t = threadIdx.x;   // 128 threads
    const float w[5]   = {0.0448f, 0.2856f, 0.3001f, 0.2363f, 0.1333f};
    const float inv[5] = {1.f / (502.f * 502.f), 1.f / (246.f * 246.f),
                          1.f / (118.f * 118.f), 1.f / (54.f * 54.f),
                          1.f / (22.f * 22.f)};
    float ms = 0.f;
    if (t < 96) {
        ms = 1.f;
        #pragma unroll
        for (int l = 0; l < 5; ++l) {
            float v = (l < 4) ? accum[l * 192 + 96 + t] : accum[l * 192 + t];
            v *= inv[l];
            v = fmaxf(v, 0.f);
            ms *= powf(v, w[l]);
        }
    }
    for (int off = 32; off > 0; off >>= 1) ms += __shfl_down(ms, off);
    int wid = t >> 6, lane = t & 63;
    if (lane == 0) red[wid] = ms;
    __syncthreads();
    if (t == 0) out[0] = 1.f - (red[0] + red[1]) * (1.f / 96.f);
}

extern "C" void kernel_launch(void* const* d_in, const int* in_sizes, int n_in,
                              void* d_out, int out_size, void* d_ws, size_t ws_size,
                              hipStream_t stream)
{
    (void)in_sizes; (void)n_in; (void)out_size; (void)ws_size;
    const float* X = (const float*)d_in[0];
    const float* Y = (const float*)d_in[1];
    float* out = (float*)d_out;
    float* ws  = (float*)d_ws;

    // Gaussian window (size 11, sigma 1.5), normalized
    GWin gw;
    {
        double g[11], s = 0.0;
        for (int i = 0; i < 11; ++i) { double d = i - 5; g[i] = exp(-(d * d) / 4.5); s += g[i]; }
        for (int i = 0; i < 11; ++i) gw.w[i] = (float)(g[i] / s);
    }

    // workspace layout (floats): accum then pyramid buffers
    float* accum = ws;                 // L0 at +0, L1..L4 at +192*(L+1)
    size_t off = 1024;
    float* p1x = ws + off; off += (size_t)96 * 256 * 256;
    float* p1y = ws + off; off += (size_t)96 * 256 * 256;
    float* p2x = ws + off; off += (size_t)96 * 128 * 128;
    float* p2y = ws + off; off += (size_t)96 * 128 * 128;
    float* p3x = ws + off; off += (size_t)96 * 64 * 64;
    float* p3y = ws + off; off += (size_t)96 * 64 * 64;
    float* p4x = ws + off; off += (size_t)96 * 32 * 32;
    float* p4y = ws + off; off += (size_t)96 * 32 * 32;

    hipMemsetAsync(accum, 0, 5 * 192 * sizeof(float), stream);

    // L0: r15 kernel (writes P1 only), 8 strips x 96 channels
    ssim_rows_kernel<<<dim3(8, 1, 96), 256, 0, stream>>>(
        X, Y, p1x, p1y, accum, 512, 502, 1, 64, 8, gw);

    // P1 -> P2, P3, P4 (hierarchical, shfl butterflies)
    pool_pyramid_kernel<<<dim3(16, 96), 256, 0, stream>>>(
        p1x, p1y, p2x, p2y, p3x, p3y, p4x, p4y);

    // L1..L4 fused: 384 + 192 + 48 + 6 = 630 blocks
    ssim_rest_kernel<<<dim3(630), 256, 0, stream>>>(
        p1x, p1y, p2x, p2y, p3x, p3y, p4x, p4y, accum, gw);

    finalize_kernel<<<1, 128, 0, stream>>>(accum, out);
}